// Round 1
// baseline (796.171 us; speedup 1.0000x reference)
//
#include <hip/hip_runtime.h>

#define D_IN 32
#define KNN  16
#define NPTS 65536
#define BATCH 2

// ---------------- Kernel A: fused TNet trunk (3->16->64) + global max over N ----
__global__ __launch_bounds__(256) void tnet_max_kernel(
    const float* __restrict__ xyz,
    const float* __restrict__ tW1, const float* __restrict__ ts1, const float* __restrict__ tb1,
    const float* __restrict__ tW2, const float* __restrict__ ts2, const float* __restrict__ tb2,
    float* __restrict__ hmax /* [BATCH*64], uint-bit atomicMax, pre-zeroed */)
{
    int flat = blockIdx.x * 256 + threadIdx.x;      // grid = BATCH*NPTS/256 exactly
    int b = flat / NPTS, n = flat % NPTS;
    const float* p = xyz + ((size_t)b * NPTS + n) * 3;
    float x0 = p[0], x1 = p[1], x2 = p[2];

    float h1[16];
#pragma unroll
    for (int c = 0; c < 16; c++) {
        float a = x0 * tW1[c] + x1 * tW1[16 + c] + x2 * tW1[32 + c];
        a = a * ts1[c] + tb1[c];
        h1[c] = a > 0.f ? a : 0.f;
    }
    float h2[64];
#pragma unroll
    for (int c = 0; c < 64; c++) {
        float a = 0.f;
#pragma unroll
        for (int i = 0; i < 16; i++) a += h1[i] * tW2[i * 64 + c];
        a = a * ts2[c] + tb2[c];
        h2[c] = a > 0.f ? a : 0.f;
    }
    // wave(64)-wide max reduce per channel
#pragma unroll
    for (int c = 0; c < 64; c++) {
        float v = h2[c];
        for (int off = 32; off; off >>= 1)
            v = fmaxf(v, __shfl_xor(v, off, 64));
        h2[c] = v;
    }
    __shared__ float red[4][64];
    int wave = threadIdx.x >> 6, lane = threadIdx.x & 63;
    if (lane == 0) {
#pragma unroll
        for (int c = 0; c < 64; c++) red[wave][c] = h2[c];
    }
    __syncthreads();
    if (threadIdx.x < 64) {  // whole block is a single batch b (NPTS % 256 == 0)
        int c = threadIdx.x;
        float m = fmaxf(fmaxf(red[0][c], red[1][c]), fmaxf(red[2][c], red[3][c]));
        atomicMax((unsigned int*)(hmax + b * 64 + c), __float_as_uint(m));  // valid: m >= 0
    }
}

// ---------------- Kernel B: TNet head (64->16->9) + identity -> 3x3 transform ---
__global__ void tnet_head_kernel(
    const float* __restrict__ hmax,
    const float* __restrict__ tW3, const float* __restrict__ ts3, const float* __restrict__ tb3,
    const float* __restrict__ tW4, const float* __restrict__ tb4,
    float* __restrict__ tmat /* [BATCH*9] */)
{
    int t = threadIdx.x;
    if (t >= BATCH * 9) return;
    int b = t / 9, j = t % 9;
    float h3[16];
#pragma unroll
    for (int c = 0; c < 16; c++) {
        float a = 0.f;
#pragma unroll
        for (int i = 0; i < 64; i++) a += hmax[b * 64 + i] * tW3[i * 16 + c];
        a = a * ts3[c] + tb3[c];
        h3[c] = a > 0.f ? a : 0.f;
    }
    float a = tb4[j];
#pragma unroll
    for (int c = 0; c < 16; c++) a += h3[c] * tW4[c * 9 + j];
    if (j == 0 || j == 4 || j == 8) a += 1.f;  // + eye(3) flattened
    tmat[b * 9 + j] = a;
}

// ---------------- Kernel C: per-point CBR(W2) on feat + xyz@t -> CBR(W1), packed
// packed[point] = [ f_nei(32) , f_xyz(3) , pad ]  : 36 floats = 9 aligned float4
__global__ __launch_bounds__(256) void prep_kernel(
    const float* __restrict__ feature, const float* __restrict__ xyz,
    const float* __restrict__ tmat,
    const float* __restrict__ W1, const float* __restrict__ s1, const float* __restrict__ b1,
    const float* __restrict__ W2, const float* __restrict__ s2, const float* __restrict__ b2,
    float* __restrict__ packed)
{
    int flat = blockIdx.x * 256 + threadIdx.x;
    int b = flat / NPTS, n = flat % NPTS;
    const float* p = xyz + ((size_t)b * NPTS + n) * 3;
    float x0 = p[0], x1 = p[1], x2 = p[2];
    float T[9];
#pragma unroll
    for (int j = 0; j < 9; j++) T[j] = tmat[b * 9 + j];
    float q[3];
#pragma unroll
    for (int j = 0; j < 3; j++) q[j] = x0 * T[j] + x1 * T[3 + j] + x2 * T[6 + j];
    float r[3];
#pragma unroll
    for (int j = 0; j < 3; j++) {
        float a = q[0] * W1[j] + q[1] * W1[3 + j] + q[2] * W1[6 + j];
        a = a * s1[j] + b1[j];
        r[j] = a > 0.f ? a : 0.f;
    }
    float f[32];
    const float* fp = feature + (size_t)b * D_IN * NPTS + n;
#pragma unroll
    for (int c = 0; c < 32; c++) f[c] = fp[(size_t)c * NPTS];  // coalesced across lanes

    float outv[36];
#pragma unroll
    for (int o = 0; o < 32; o++) {
        float a = 0.f;
#pragma unroll
        for (int c = 0; c < 32; c++) a += f[c] * W2[c * 32 + o];  // W2 via s_load (uniform)
        a = a * s2[o] + b2[o];
        outv[o] = a > 0.f ? a : 0.f;
    }
    outv[32] = r[0]; outv[33] = r[1]; outv[34] = r[2]; outv[35] = 0.f;
    float4* dst = (float4*)(packed + (size_t)flat * 36);
    const float4* src = (const float4*)outv;
#pragma unroll
    for (int i = 0; i < 9; i++) dst[i] = src[i];
}

// ---------------- Kernel D: gather K neighbors, 35->32 CBR, max over K, concat, W4
__global__ __launch_bounds__(256) void main_kernel(
    const float* __restrict__ feature, const int* __restrict__ nidx,
    const float* __restrict__ packed,
    const float* __restrict__ W3, const float* __restrict__ s3, const float* __restrict__ b3,
    const float* __restrict__ W4, const float* __restrict__ s4, const float* __restrict__ b4,
    float* __restrict__ out)
{
    int flat = blockIdx.x * 256 + threadIdx.x;
    int b = flat / NPTS, n = flat % NPTS;

    int idx[KNN];
    const int4* ip = (const int4*)(nidx + (size_t)flat * KNN);  // 64B aligned
#pragma unroll
    for (int i = 0; i < 4; i++) {
        int4 v = ip[i];
        idx[4 * i] = v.x; idx[4 * i + 1] = v.y; idx[4 * i + 2] = v.z; idx[4 * i + 3] = v.w;
    }

    float m[32];
#pragma unroll
    for (int o = 0; o < 32; o++) m[o] = 0.f;  // max of ReLU outputs is >= 0

    for (int k = 0; k < KNN; k++) {
        const float4* vp = (const float4*)(packed + ((size_t)b * NPTS + idx[k]) * 36);
        float v[36];
        float4* vv = (float4*)v;
#pragma unroll
        for (int i = 0; i < 9; i++) vv[i] = vp[i];
        float acc[32];
#pragma unroll
        for (int o = 0; o < 32; o++) acc[o] = 0.f;
#pragma unroll
        for (int ci = 0; ci < 35; ci++) {
#pragma unroll
            for (int o = 0; o < 32; o++) acc[o] += v[ci] * W3[ci * 32 + o];  // s_load weights
        }
#pragma unroll
        for (int o = 0; o < 32; o++) {
            float a = acc[o] * s3[o] + b3[o];
            a = a > 0.f ? a : 0.f;
            m[o] = fmaxf(m[o], a);
        }
    }

    float f[32];
    const float* fp = feature + (size_t)b * D_IN * NPTS + n;
#pragma unroll
    for (int c = 0; c < 32; c++) f[c] = fp[(size_t)c * NPTS];

    float* op = out + (size_t)b * D_IN * NPTS + n;
#pragma unroll
    for (int o = 0; o < 32; o++) {
        float a = 0.f;
#pragma unroll
        for (int c = 0; c < 32; c++) a += f[c] * W4[c * 32 + o];
#pragma unroll
        for (int c = 0; c < 32; c++) a += m[c] * W4[(32 + c) * 32 + o];
        a = a * s4[o] + b4[o];
        op[(size_t)o * NPTS] = a > 0.f ? a : 0.f;  // coalesced across lanes
    }
}

extern "C" void kernel_launch(void* const* d_in, const int* in_sizes, int n_in,
                              void* d_out, int out_size, void* d_ws, size_t ws_size,
                              hipStream_t stream)
{
    const float* feature = (const float*)d_in[0];
    const float* xyz     = (const float*)d_in[1];
    const int*   nidx    = (const int*)d_in[2];
    const float* tW1 = (const float*)d_in[3];
    const float* ts1 = (const float*)d_in[4];
    const float* tb1 = (const float*)d_in[5];
    const float* tW2 = (const float*)d_in[6];
    const float* ts2 = (const float*)d_in[7];
    const float* tb2 = (const float*)d_in[8];
    const float* tW3 = (const float*)d_in[9];
    const float* ts3 = (const float*)d_in[10];
    const float* tb3 = (const float*)d_in[11];
    const float* tW4 = (const float*)d_in[12];
    const float* tb4 = (const float*)d_in[13];
    const float* W1  = (const float*)d_in[14];
    const float* s1  = (const float*)d_in[15];
    const float* b1  = (const float*)d_in[16];
    const float* W2  = (const float*)d_in[17];
    const float* s2  = (const float*)d_in[18];
    const float* b2  = (const float*)d_in[19];
    const float* W3  = (const float*)d_in[20];
    const float* s3  = (const float*)d_in[21];
    const float* b3  = (const float*)d_in[22];
    const float* W4  = (const float*)d_in[23];
    const float* s4  = (const float*)d_in[24];
    const float* b4  = (const float*)d_in[25];

    float* ws     = (float*)d_ws;
    float* hmax   = ws;          // 128 floats (BATCH*64)
    float* tmat   = ws + 128;    // 18 floats
    float* packed = ws + 256;    // BATCH*NPTS*36 floats (~18.9 MB), 16B-aligned

    hipMemsetAsync(hmax, 0, 128 * sizeof(float), stream);  // exact init for >=0 max

    int total = BATCH * NPTS;
    tnet_max_kernel<<<total / 256, 256, 0, stream>>>(xyz, tW1, ts1, tb1, tW2, ts2, tb2, hmax);
    tnet_head_kernel<<<1, 64, 0, stream>>>(hmax, tW3, ts3, tb3, tW4, tb4, tmat);
    prep_kernel<<<total / 256, 256, 0, stream>>>(feature, xyz, tmat, W1, s1, b1, W2, s2, b2, packed);
    main_kernel<<<total / 256, 256, 0, stream>>>(feature, nidx, packed, W3, s3, b3, W4, s4, b4,
                                                 (float*)d_out);
}

// Round 2
// 214.769 us; speedup vs baseline: 3.7071x; 3.7071x over previous
//
#include <hip/hip_runtime.h>

#define NPTS  65536
#define BATCH 2
#define TOTAL (BATCH * NPTS)

typedef __attribute__((ext_vector_type(8)))  short short8;
typedef __attribute__((ext_vector_type(16))) float float16;

union F8 { uint4 u; short8 s; };

// ws byte offsets
#define WS_HMAX    0                      // 512 B
#define WS_TMAT    512                    // 72 B
#define WS_TW1F    1024                   // 192 B fp32[48]
#define WS_W1F     1216                   // 36 B  fp32[9]
#define WS_TW2FT   1536                   // bf16[64][16]  (n-major)
#define WS_W2FT    3584                   // bf16[32][32]
#define WS_W3FT    5632                   // bf16[32][48]  (rows 35..47 zero)
#define WS_W4FT    8704                   // bf16[32][64]
#define WS_TABLE1  16384                  // bf16[TOTAL][48]: [f_nei(32), f_xyz(3), 0-pad]
#define WS_TABLE2  (16384 + TOTAL * 96)   // bf16[TOTAL][64]: [feat(32), m(32)]

__device__ __forceinline__ unsigned short f2bf(float x) {
    unsigned u = __float_as_uint(x);
    return (unsigned short)((u + 0x7FFFu + ((u >> 16) & 1u)) >> 16);
}
__device__ __forceinline__ unsigned pk2(float a, float b) {
    return (unsigned)f2bf(a) | ((unsigned)f2bf(b) << 16);
}
__device__ __forceinline__ float relu(float x) { return x > 0.f ? x : 0.f; }

// ---------- K0: fold BN scales into weights, convert to bf16 frag-friendly layouts
__global__ void k0_fold(const float* __restrict__ tW1, const float* __restrict__ ts1,
                        const float* __restrict__ tW2, const float* __restrict__ ts2,
                        const float* __restrict__ W1,  const float* __restrict__ s1,
                        const float* __restrict__ W2,  const float* __restrict__ s2,
                        const float* __restrict__ W3,  const float* __restrict__ s3,
                        const float* __restrict__ W4,  const float* __restrict__ s4,
                        char* ws)
{
    int t = threadIdx.x;
    float* tW1f = (float*)(ws + WS_TW1F);
    float* W1f  = (float*)(ws + WS_W1F);
    unsigned short* tW2fT = (unsigned short*)(ws + WS_TW2FT);
    unsigned short* W2fT  = (unsigned short*)(ws + WS_W2FT);
    unsigned short* W3fT  = (unsigned short*)(ws + WS_W3FT);
    unsigned short* W4fT  = (unsigned short*)(ws + WS_W4FT);
    for (int i = t; i < 48; i += 256) tW1f[i] = tW1[i] * ts1[i & 15];
    for (int i = t; i < 9;  i += 256) W1f[i]  = W1[i] * s1[i % 3];
    for (int i = t; i < 64 * 16; i += 256) { int n = i >> 4, k = i & 15; tW2fT[i] = f2bf(tW2[k * 64 + n] * ts2[n]); }
    for (int i = t; i < 32 * 32; i += 256) { int n = i >> 5, k = i & 31; W2fT[i] = f2bf(W2[k * 32 + n] * s2[n]); }
    for (int i = t; i < 32 * 48; i += 256) { int n = i / 48, k = i % 48; W3fT[i] = (k < 35) ? f2bf(W3[k * 32 + n] * s3[n]) : (unsigned short)0; }
    for (int i = t; i < 32 * 64; i += 256) { int n = i >> 6, k = i & 63; W4fT[i] = f2bf(W4[k * 32 + n] * s4[n]); }
}

// ---------- K1: tnet trunk (3->16->64) via MFMA, max over N -> hmax[B*64]
__global__ __launch_bounds__(256) void k1_tnet(const float* __restrict__ xyz,
        const float* __restrict__ tb1, const float* __restrict__ tb2,
        const char* __restrict__ ws, float* __restrict__ hmax)
{
    const float* tW1f = (const float*)(ws + WS_TW1F);
    const unsigned short* tW2fT = (const unsigned short*)(ws + WS_TW2FT);
    int lane = threadIdx.x & 63;
    int wave = (blockIdx.x * 256 + threadIdx.x) >> 6;   // 0..1023, 128 pts each
    int col = lane & 31, h = lane >> 5;

    float aw0[8], aw1[8], aw2[8], bb[8];
#pragma unroll
    for (int j = 0; j < 8; j++) {
        int k = 8 * h + j;
        aw0[j] = tW1f[k]; aw1[j] = tW1f[16 + k]; aw2[j] = tW1f[32 + k];
        bb[j] = tb1[k];
    }
    F8 bf0, bf1;
    bf0.u = *(const uint4*)(tW2fT + col * 16 + 8 * h);
    bf1.u = *(const uint4*)(tW2fT + (32 + col) * 16 + 8 * h);

    float16 m0, m1;
#pragma unroll
    for (int i = 0; i < 16; i++) { m0[i] = -1e30f; m1[i] = -1e30f; }
    int b = (wave * 128) >> 16;   // wave never crosses batch (128 | 65536)

    for (int g = 0; g < 4; g++) {
        int base = wave * 128 + g * 32;
        const float* xp = xyz + (size_t)(base + col) * 3;
        float x0 = xp[0], x1 = xp[1], x2 = xp[2];
        float hv[8];
#pragma unroll
        for (int j = 0; j < 8; j++)
            hv[j] = relu(x0 * aw0[j] + x1 * aw1[j] + x2 * aw2[j] + bb[j]);
        F8 af;
        af.u.x = pk2(hv[0], hv[1]); af.u.y = pk2(hv[2], hv[3]);
        af.u.z = pk2(hv[4], hv[5]); af.u.w = pk2(hv[6], hv[7]);
        float16 z;
#pragma unroll
        for (int i = 0; i < 16; i++) z[i] = 0.f;
        float16 c0 = __builtin_amdgcn_mfma_f32_32x32x16_bf16(af.s, bf0.s, z, 0, 0, 0);
        float16 c1 = __builtin_amdgcn_mfma_f32_32x32x16_bf16(af.s, bf1.s, z, 0, 0, 0);
#pragma unroll
        for (int i = 0; i < 16; i++) { m0[i] = fmaxf(m0[i], c0[i]); m1[i] = fmaxf(m1[i], c1[i]); }
    }
    float v0 = m0[0], v1 = m1[0];
#pragma unroll
    for (int i = 1; i < 16; i++) { v0 = fmaxf(v0, m0[i]); v1 = fmaxf(v1, m1[i]); }
    v0 = fmaxf(v0, __shfl_xor(v0, 32));
    v1 = fmaxf(v1, __shfl_xor(v1, 32));
    v0 = relu(v0 + tb2[col]);
    v1 = relu(v1 + tb2[32 + col]);
    if (h == 0) {
        atomicMax((unsigned*)(hmax + b * 64 + col), __float_as_uint(v0));
        atomicMax((unsigned*)(hmax + b * 64 + 32 + col), __float_as_uint(v1));
    }
}

// ---------- K2: tnet head (64->16->9) + identity (tiny, fp32 VALU)
__global__ void k2_head(const float* __restrict__ hmax,
    const float* __restrict__ tW3, const float* __restrict__ ts3, const float* __restrict__ tb3,
    const float* __restrict__ tW4, const float* __restrict__ tb4, float* __restrict__ tmat)
{
    int t = threadIdx.x;
    if (t >= BATCH * 9) return;
    int b = t / 9, j = t % 9;
    float h3[16];
#pragma unroll
    for (int c = 0; c < 16; c++) {
        float a = 0.f;
#pragma unroll
        for (int i = 0; i < 64; i++) a += hmax[b * 64 + i] * tW3[i * 16 + c];
        h3[c] = relu(a * ts3[c] + tb3[c]);
    }
    float a = tb4[j];
#pragma unroll
    for (int c = 0; c < 16; c++) a += h3[c] * tW4[c * 9 + j];
    if (j == 0 || j == 4 || j == 8) a += 1.f;
    tmat[b * 9 + j] = a;
}

// ---------- K3: f_nei = cbr(feat@W2) via MFMA -> table1 cols 0..31; raw feat bf16 -> table2 cols 0..31
__global__ __launch_bounds__(256) void k3_prep(const float* __restrict__ feature,
        const float* __restrict__ b2, char* ws)
{
    const unsigned short* W2fT = (const unsigned short*)(ws + WS_W2FT);
    unsigned short* table1 = (unsigned short*)(ws + WS_TABLE1);
    unsigned short* table2 = (unsigned short*)(ws + WS_TABLE2);
    int lane = threadIdx.x & 63;
    int wave = (blockIdx.x * 256 + threadIdx.x) >> 6;   // 0..511
    int col = lane & 31, h = lane >> 5;
    F8 w0, w1;
    w0.u = *(const uint4*)(W2fT + col * 32 + 8 * h);
    w1.u = *(const uint4*)(W2fT + col * 32 + 16 + 8 * h);
    float b2v = b2[col];
    for (int tt = 0; tt < 8; tt++) {
        int base = (wave * 8 + tt) * 32;
        int b = base >> 16;
        int n = base + col;              // global point = A row
        int nl = n & (NPTS - 1);
        const float* fb = feature + (size_t)(b * 32) * NPTS + nl;
        float v[8];
        F8 a0, a1;
#pragma unroll
        for (int j = 0; j < 8; j++) v[j] = fb[(size_t)(8 * h + j) * NPTS];
        a0.u.x = pk2(v[0], v[1]); a0.u.y = pk2(v[2], v[3]); a0.u.z = pk2(v[4], v[5]); a0.u.w = pk2(v[6], v[7]);
#pragma unroll
        for (int j = 0; j < 8; j++) v[j] = fb[(size_t)(16 + 8 * h + j) * NPTS];
        a1.u.x = pk2(v[0], v[1]); a1.u.y = pk2(v[2], v[3]); a1.u.z = pk2(v[4], v[5]); a1.u.w = pk2(v[6], v[7]);
        *(uint4*)(table2 + (size_t)n * 64 + 8 * h) = a0.u;        // raw feat bf16
        *(uint4*)(table2 + (size_t)n * 64 + 16 + 8 * h) = a1.u;
        float16 acc;
#pragma unroll
        for (int i = 0; i < 16; i++) acc[i] = 0.f;
        acc = __builtin_amdgcn_mfma_f32_32x32x16_bf16(a0.s, w0.s, acc, 0, 0, 0);
        acc = __builtin_amdgcn_mfma_f32_32x32x16_bf16(a1.s, w1.s, acc, 0, 0, 0);
#pragma unroll
        for (int r = 0; r < 16; r++) {
            int row = (r & 3) + 8 * (r >> 2) + 4 * h;
            table1[(size_t)(base + row) * 48 + col] = f2bf(relu(acc[r] + b2v));
        }
    }
}

// ---------- K3b: f_xyz = cbr((xyz@t)@W1) -> table1 cols 32..34, zero-pad 35..47
__global__ __launch_bounds__(256) void k3b_xyz(const float* __restrict__ xyz,
        const float* __restrict__ b1, char* ws)
{
    const float* tmat = (const float*)(ws + WS_TMAT);
    const float* W1f  = (const float*)(ws + WS_W1F);
    unsigned short* table1 = (unsigned short*)(ws + WS_TABLE1);
    int flat = blockIdx.x * 256 + threadIdx.x;
    int b = flat >> 16;                   // block uniform (256 | 65536)
    const float* xp = xyz + (size_t)flat * 3;
    float x0 = xp[0], x1 = xp[1], x2 = xp[2];
    float T[9];
#pragma unroll
    for (int j = 0; j < 9; j++) T[j] = tmat[b * 9 + j];
    float q0 = x0 * T[0] + x1 * T[3] + x2 * T[6];
    float q1 = x0 * T[1] + x1 * T[4] + x2 * T[7];
    float q2 = x0 * T[2] + x1 * T[5] + x2 * T[8];
    float r0 = relu(q0 * W1f[0] + q1 * W1f[3] + q2 * W1f[6] + b1[0]);
    float r1 = relu(q0 * W1f[1] + q1 * W1f[4] + q2 * W1f[7] + b1[1]);
    float r2 = relu(q0 * W1f[2] + q1 * W1f[5] + q2 * W1f[8] + b1[2]);
    uint4 u; u.x = pk2(r0, r1); u.y = pk2(r2, 0.f); u.z = 0u; u.w = 0u;
    *(uint4*)(table1 + (size_t)flat * 48 + 32) = u;
    uint4 zz; zz.x = zz.y = zz.z = zz.w = 0u;
    *(uint4*)(table1 + (size_t)flat * 48 + 40) = zz;
}

// ---------- K4: gather 16 neighbors x 2 points = 32 rows, K=48 GEMM, max over K -> table2 cols 32..63
__global__ __launch_bounds__(256) void k4_main(const int* __restrict__ nidx,
        const float* __restrict__ b3, char* ws)
{
    const unsigned short* W3fT   = (const unsigned short*)(ws + WS_W3FT);
    const unsigned short* table1 = (const unsigned short*)(ws + WS_TABLE1);
    unsigned short* table2       = (unsigned short*)(ws + WS_TABLE2);
    int lane = threadIdx.x & 63;
    int wave = (blockIdx.x * 256 + threadIdx.x) >> 6;   // 0..8191
    int col = lane & 31, h = lane >> 5;
    F8 w0, w1, w2;
    w0.u = *(const uint4*)(W3fT + col * 48 + 8 * h);
    w1.u = *(const uint4*)(W3fT + col * 48 + 16 + 8 * h);
    w2.u = *(const uint4*)(W3fT + col * 48 + 32 + 8 * h);
    float b3v = b3[col];
    for (int gg = 0; gg < 8; gg++) {
        int g = wave * 8 + gg;
        int base_pt = g * 2;
        int b = base_pt >> 16;
        int pt = base_pt + (col >> 4);                  // A row -> (point, k) pair
        int idx = nidx[pt * 16 + (col & 15)];
        const unsigned short* ap = table1 + (size_t)((b << 16) + idx) * 48 + 8 * h;
        F8 a0, a1, a2;
        a0.u = *(const uint4*)(ap);
        a1.u = *(const uint4*)(ap + 16);
        a2.u = *(const uint4*)(ap + 32);
        float16 acc;
#pragma unroll
        for (int i = 0; i < 16; i++) acc[i] = 0.f;
        acc = __builtin_amdgcn_mfma_f32_32x32x16_bf16(a0.s, w0.s, acc, 0, 0, 0);
        acc = __builtin_amdgcn_mfma_f32_32x32x16_bf16(a1.s, w1.s, acc, 0, 0, 0);
        acc = __builtin_amdgcn_mfma_f32_32x32x16_bf16(a2.s, w2.s, acc, 0, 0, 0);
        // rows 0..15 = point A (regs 0..7), rows 16..31 = point B (regs 8..15)
        float vA = acc[0], vB = acc[8];
#pragma unroll
        for (int r = 1; r < 8; r++) { vA = fmaxf(vA, acc[r]); vB = fmaxf(vB, acc[8 + r]); }
        vA = fmaxf(vA, __shfl_xor(vA, 32));
        vB = fmaxf(vB, __shfl_xor(vB, 32));
        vA = relu(vA + b3v);                            // b col-uniform: add after max
        vB = relu(vB + b3v);
        float val = h ? vB : vA;
        table2[(size_t)(base_pt + h) * 64 + 32 + col] = f2bf(val);
    }
}

// ---------- K5: out = cbr([feat, m] @ W4), transposed GEMM (cols=points) -> coalesced store
__global__ __launch_bounds__(256) void k5_out(const float* __restrict__ b4,
        const char* __restrict__ ws, float* __restrict__ out)
{
    const unsigned short* W4fT   = (const unsigned short*)(ws + WS_W4FT);
    const unsigned short* table2 = (const unsigned short*)(ws + WS_TABLE2);
    int lane = threadIdx.x & 63;
    int wave = (blockIdx.x * 256 + threadIdx.x) >> 6;   // 0..511
    int col = lane & 31, h = lane >> 5;
    F8 aw[4];
#pragma unroll
    for (int t = 0; t < 4; t++)
        aw[t].u = *(const uint4*)(W4fT + col * 64 + 16 * t + 8 * h);
    float b4v[16];
#pragma unroll
    for (int r = 0; r < 16; r++) b4v[r] = b4[(r & 3) + 8 * (r >> 2) + 4 * h];
    for (int tt = 0; tt < 8; tt++) {
        int base = (wave * 8 + tt) * 32;
        int b = base >> 16;
        int p = base + col;                             // B col = point
        int nl = p & (NPTS - 1);
        const unsigned short* bp = table2 + (size_t)p * 64 + 8 * h;
        F8 x0, x1, x2, x3;
        x0.u = *(const uint4*)(bp);
        x1.u = *(const uint4*)(bp + 16);
        x2.u = *(const uint4*)(bp + 32);
        x3.u = *(const uint4*)(bp + 48);
        float16 acc;
#pragma unroll
        for (int i = 0; i < 16; i++) acc[i] = 0.f;
        acc = __builtin_amdgcn_mfma_f32_32x32x16_bf16(aw[0].s, x0.s, acc, 0, 0, 0);
        acc = __builtin_amdgcn_mfma_f32_32x32x16_bf16(aw[1].s, x1.s, acc, 0, 0, 0);
        acc = __builtin_amdgcn_mfma_f32_32x32x16_bf16(aw[2].s, x2.s, acc, 0, 0, 0);
        acc = __builtin_amdgcn_mfma_f32_32x32x16_bf16(aw[3].s, x3.s, acc, 0, 0, 0);
        float* ob = out + (size_t)(b * 32) * NPTS + nl;
#pragma unroll
        for (int r = 0; r < 16; r++) {
            int o = (r & 3) + 8 * (r >> 2) + 4 * h;     // C row = out channel
            ob[(size_t)o * NPTS] = relu(acc[r] + b4v[r]);
        }
    }
}

extern "C" void kernel_launch(void* const* d_in, const int* in_sizes, int n_in,
                              void* d_out, int out_size, void* d_ws, size_t ws_size,
                              hipStream_t stream)
{
    const float* feature = (const float*)d_in[0];
    const float* xyz     = (const float*)d_in[1];
    const int*   nidx    = (const int*)d_in[2];
    const float* tW1 = (const float*)d_in[3];
    const float* ts1 = (const float*)d_in[4];
    const float* tb1 = (const float*)d_in[5];
    const float* tW2 = (const float*)d_in[6];
    const float* ts2 = (const float*)d_in[7];
    const float* tb2 = (const float*)d_in[8];
    const float* tW3 = (const float*)d_in[9];
    const float* ts3 = (const float*)d_in[10];
    const float* tb3 = (const float*)d_in[11];
    const float* tW4 = (const float*)d_in[12];
    const float* tb4 = (const float*)d_in[13];
    const float* W1  = (const float*)d_in[14];
    const float* s1  = (const float*)d_in[15];
    const float* b1  = (const float*)d_in[16];
    const float* W2  = (const float*)d_in[17];
    const float* s2  = (const float*)d_in[18];
    const float* b2  = (const float*)d_in[19];
    const float* W3  = (const float*)d_in[20];
    const float* s3  = (const float*)d_in[21];
    const float* b3  = (const float*)d_in[22];
    const float* W4  = (const float*)d_in[23];
    const float* s4  = (const float*)d_in[24];
    const float* b4  = (const float*)d_in[25];
    (void)in_sizes; (void)n_in; (void)out_size; (void)ws_size;

    char* ws = (char*)d_ws;
    float* hmax = (float*)(ws + WS_HMAX);
    float* tmat = (float*)(ws + WS_TMAT);

    hipMemsetAsync(hmax, 0, 512, stream);
    k0_fold<<<1, 256, 0, stream>>>(tW1, ts1, tW2, ts2, W1, s1, W2, s2, W3, s3, W4, s4, ws);
    k1_tnet<<<256, 256, 0, stream>>>(xyz, tb1, tb2, ws, hmax);
    k2_head<<<1, 64, 0, stream>>>(hmax, tW3, ts3, tb3, tW4, tb4, tmat);
    k3_prep<<<128, 256, 0, stream>>>(feature, b2, ws);
    k3b_xyz<<<TOTAL / 256, 256, 0, stream>>>(xyz, b1, ws);
    k4_main<<<2048, 256, 0, stream>>>(nidx, b3, ws);
    k5_out<<<128, 256, 0, stream>>>(b4, ws, (float*)d_out);
}

// Round 3
// 204.500 us; speedup vs baseline: 3.8933x; 1.0502x over previous
//
#include <hip/hip_runtime.h>

#define NPTS  65536
#define BATCH 2
#define TOTAL (BATCH * NPTS)
#define T1S   40   // table1 row stride in bf16 elems (80 B): [f_nei(32), f_xyz(3), 0-pad(5)]
#define T2S   64   // table2 row stride in bf16 elems (128 B): [feat(32), m(32)]

typedef __attribute__((ext_vector_type(8)))  short short8;
typedef __attribute__((ext_vector_type(16))) float float16;
union F8 { uint4 u; short8 s; };

// ws byte offsets
#define WS_HMAX   0        // fp32[128]
#define WS_TW1F   1024     // fp32[48]   tW1*ts1
#define WS_W1F    1216     // fp32[9]    W1*s1
#define WS_TW2FT  1536     // bf16[64][16]  B-op for k1 ([co][ci])
#define WS_W2FAT  3584     // bf16[32][32]  A-op for k3 ([co][ci])
#define WS_W3FT   5632     // bf16[32][40]  B-op for k4 ([co][ci40], ci>=35 zero)
#define WS_W4FT   8192     // bf16[32][64]  A-op for k5 ([co][ci])
#define WS_TABLE1 16384                      // bf16[TOTAL][40]
#define WS_TABLE2 (16384 + TOTAL * 80)       // bf16[TOTAL][64]

__device__ __forceinline__ unsigned short f2bf(float x) {
    unsigned u = __float_as_uint(x);
    return (unsigned short)((u + 0x7FFFu + ((u >> 16) & 1u)) >> 16);
}
__device__ __forceinline__ unsigned pk2(float a, float b) {
    return (unsigned)f2bf(a) | ((unsigned)f2bf(b) << 16);
}
__device__ __forceinline__ float relu(float x) { return x > 0.f ? x : 0.f; }

// ---------- K0: zero hmax + fold BN scales into bf16 weight tables ----------
__global__ void k0_fold(const float* __restrict__ tW1, const float* __restrict__ ts1,
                        const float* __restrict__ tW2, const float* __restrict__ ts2,
                        const float* __restrict__ W1,  const float* __restrict__ s1,
                        const float* __restrict__ W2,  const float* __restrict__ s2,
                        const float* __restrict__ W3,  const float* __restrict__ s3,
                        const float* __restrict__ W4,  const float* __restrict__ s4,
                        char* ws)
{
    int t = threadIdx.x;
    float* hmax = (float*)(ws + WS_HMAX);
    float* tW1f = (float*)(ws + WS_TW1F);
    float* W1f  = (float*)(ws + WS_W1F);
    unsigned short* tW2fT = (unsigned short*)(ws + WS_TW2FT);
    unsigned short* W2fAT = (unsigned short*)(ws + WS_W2FAT);
    unsigned short* W3fT  = (unsigned short*)(ws + WS_W3FT);
    unsigned short* W4fT  = (unsigned short*)(ws + WS_W4FT);
    if (t < 128) hmax[t] = 0.f;
    for (int i = t; i < 48; i += 256) tW1f[i] = tW1[i] * ts1[i & 15];
    for (int i = t; i < 9;  i += 256) W1f[i]  = W1[i] * s1[i % 3];
    for (int i = t; i < 64 * 16; i += 256) { int n = i >> 4, k = i & 15; tW2fT[i] = f2bf(tW2[k * 64 + n] * ts2[n]); }
    for (int i = t; i < 32 * 32; i += 256) { int m = i >> 5, k = i & 31; W2fAT[i] = f2bf(W2[k * 32 + m] * s2[m]); }
    for (int i = t; i < 32 * 40; i += 256) { int n = i / 40, k = i % 40; W3fT[i] = (k < 35) ? f2bf(W3[k * 32 + n] * s3[n]) : (unsigned short)0; }
    for (int i = t; i < 32 * 64; i += 256) { int n = i >> 6, k = i & 63; W4fT[i] = f2bf(W4[k * 32 + n] * s4[n]); }
}

// ---------- K1: tnet trunk (3->16->64) via MFMA, max over N -> hmax[B*64] ----
__global__ __launch_bounds__(256) void k1_tnet(const float* __restrict__ xyz,
        const float* __restrict__ tb1, const float* __restrict__ tb2,
        const char* __restrict__ ws, float* __restrict__ hmax)
{
    const float* tW1f = (const float*)(ws + WS_TW1F);
    const unsigned short* tW2fT = (const unsigned short*)(ws + WS_TW2FT);
    int lane = threadIdx.x & 63;
    int wave = (blockIdx.x * 256 + threadIdx.x) >> 6;   // 0..2047, 64 pts each
    int col = lane & 31, h = lane >> 5;

    float aw0[8], aw1[8], aw2[8], bb[8];
#pragma unroll
    for (int j = 0; j < 8; j++) {
        int k = 8 * h + j;
        aw0[j] = tW1f[k]; aw1[j] = tW1f[16 + k]; aw2[j] = tW1f[32 + k];
        bb[j] = tb1[k];
    }
    F8 bf0, bf1;
    bf0.u = *(const uint4*)(tW2fT + col * 16 + 8 * h);
    bf1.u = *(const uint4*)(tW2fT + (32 + col) * 16 + 8 * h);

    float16 m0, m1;
#pragma unroll
    for (int i = 0; i < 16; i++) { m0[i] = -1e30f; m1[i] = -1e30f; }
    int b = (wave * 64) >> 16;   // wave never crosses batch (64 | 65536)

    for (int g = 0; g < 2; g++) {
        int base = wave * 64 + g * 32;
        const float* xp = xyz + (size_t)(base + col) * 3;
        float x0 = xp[0], x1 = xp[1], x2 = xp[2];
        float hv[8];
#pragma unroll
        for (int j = 0; j < 8; j++)
            hv[j] = relu(x0 * aw0[j] + x1 * aw1[j] + x2 * aw2[j] + bb[j]);
        F8 af;
        af.u.x = pk2(hv[0], hv[1]); af.u.y = pk2(hv[2], hv[3]);
        af.u.z = pk2(hv[4], hv[5]); af.u.w = pk2(hv[6], hv[7]);
        float16 z;
#pragma unroll
        for (int i = 0; i < 16; i++) z[i] = 0.f;
        float16 c0 = __builtin_amdgcn_mfma_f32_32x32x16_bf16(af.s, bf0.s, z, 0, 0, 0);
        float16 c1 = __builtin_amdgcn_mfma_f32_32x32x16_bf16(af.s, bf1.s, z, 0, 0, 0);
#pragma unroll
        for (int i = 0; i < 16; i++) { m0[i] = fmaxf(m0[i], c0[i]); m1[i] = fmaxf(m1[i], c1[i]); }
    }
    float v0 = m0[0], v1 = m1[0];
#pragma unroll
    for (int i = 1; i < 16; i++) { v0 = fmaxf(v0, m0[i]); v1 = fmaxf(v1, m1[i]); }
    v0 = fmaxf(v0, __shfl_xor(v0, 32));
    v1 = fmaxf(v1, __shfl_xor(v1, 32));
    v0 = relu(v0 + tb2[col]);
    v1 = relu(v1 + tb2[32 + col]);
    if (h == 0) {
        atomicMax((unsigned*)(hmax + b * 64 + col), __float_as_uint(v0));
        atomicMax((unsigned*)(hmax + b * 64 + 32 + col), __float_as_uint(v1));
    }
}

// ---------- K3: per-wave tnet head + f_nei GEMM (C rows=channels) + raw feat + f_xyz
__global__ __launch_bounds__(256) void k3_prep(const float* __restrict__ feature,
        const float* __restrict__ xyz,
        const float* __restrict__ tW3, const float* __restrict__ ts3, const float* __restrict__ tb3,
        const float* __restrict__ tW4, const float* __restrict__ tb4,
        const float* __restrict__ b1,  const float* __restrict__ b2, char* ws)
{
    const float* hmax  = (const float*)(ws + WS_HMAX);
    const float* W1f   = (const float*)(ws + WS_W1F);
    const unsigned short* W2fAT = (const unsigned short*)(ws + WS_W2FAT);
    unsigned short* table1 = (unsigned short*)(ws + WS_TABLE1);
    unsigned short* table2 = (unsigned short*)(ws + WS_TABLE2);
    int lane = threadIdx.x & 63;
    int wave = (blockIdx.x * 256 + threadIdx.x) >> 6;   // 0..4095, 32 pts each
    int col = lane & 31, h = lane >> 5;
    int base = wave * 32;
    int b = base >> 16;
    int pt = base + col;                 // this lane's point (for B-cols / xyz / stores)

    // --- A-fragments: folded W2^T ([co][ci]) ---
    F8 a0, a1;
    a0.u = *(const uint4*)(W2fAT + col * 32 + 8 * h);
    a1.u = *(const uint4*)(W2fAT + col * 32 + 16 + 8 * h);

    // --- B-fragments: feat channels for point `pt` (+ raw bf16 copy to table2) ---
    const float* fb = feature + (size_t)b * 32 * NPTS + (pt & (NPTS - 1));
    float v[8];
    F8 b0, b1f;
#pragma unroll
    for (int j = 0; j < 8; j++) v[j] = fb[(size_t)(8 * h + j) * NPTS];
    b0.u.x = pk2(v[0], v[1]); b0.u.y = pk2(v[2], v[3]); b0.u.z = pk2(v[4], v[5]); b0.u.w = pk2(v[6], v[7]);
#pragma unroll
    for (int j = 0; j < 8; j++) v[j] = fb[(size_t)(16 + 8 * h + j) * NPTS];
    b1f.u.x = pk2(v[0], v[1]); b1f.u.y = pk2(v[2], v[3]); b1f.u.z = pk2(v[4], v[5]); b1f.u.w = pk2(v[6], v[7]);
    *(uint4*)(table2 + (size_t)pt * T2S + 8 * h) = b0.u;
    *(uint4*)(table2 + (size_t)pt * T2S + 16 + 8 * h) = b1f.u;

    float16 acc;
#pragma unroll
    for (int i = 0; i < 16; i++) acc[i] = 0.f;
    acc = __builtin_amdgcn_mfma_f32_32x32x16_bf16(a0.s, b0.s, acc, 0, 0, 0);
    acc = __builtin_amdgcn_mfma_f32_32x32x16_bf16(a1.s, b1f.s, acc, 0, 0, 0);

    // epilogue: C[m=co][n=pt]; lane holds 4 quads of contiguous channels
    float b2v[16];
#pragma unroll
    for (int r = 0; r < 16; r++) b2v[r] = b2[(r & 3) + 8 * (r >> 2) + 4 * h];
#pragma unroll
    for (int q = 0; q < 4; q++) {
        int r = 4 * q;
        uint2 u;
        u.x = pk2(relu(acc[r] + b2v[r]), relu(acc[r + 1] + b2v[r + 1]));
        u.y = pk2(relu(acc[r + 2] + b2v[r + 2]), relu(acc[r + 3] + b2v[r + 3]));
        *(uint2*)(table1 + (size_t)pt * T1S + 8 * q + 4 * h) = u;
    }

    // --- tnet head (per-wave recompute, ~150 instrs): T = head(hmax[b]) ---
    int lc = lane & 15;
    float ha = 0.f;
    for (int i = 0; i < 64; i++) ha += hmax[b * 64 + i] * tW3[i * 16 + lc];
    float h3 = relu(ha * ts3[lc] + tb3[lc]);
    float T[9];
#pragma unroll
    for (int j = 0; j < 9; j++) T[j] = tb4[j];
    for (int c = 0; c < 16; c++) {
        float hc = __shfl(h3, c, 64);
#pragma unroll
        for (int j = 0; j < 9; j++) T[j] += hc * tW4[c * 9 + j];
    }
    T[0] += 1.f; T[4] += 1.f; T[8] += 1.f;

    // --- f_xyz for this lane's point ---
    const float* xp = xyz + (size_t)pt * 3;
    float x0 = xp[0], x1 = xp[1], x2 = xp[2];
    float q0 = x0 * T[0] + x1 * T[3] + x2 * T[6];
    float q1 = x0 * T[1] + x1 * T[4] + x2 * T[7];
    float q2 = x0 * T[2] + x1 * T[5] + x2 * T[8];
    float r0 = relu(q0 * W1f[0] + q1 * W1f[3] + q2 * W1f[6] + b1[0]);
    float r1 = relu(q0 * W1f[1] + q1 * W1f[4] + q2 * W1f[7] + b1[1]);
    float r2 = relu(q0 * W1f[2] + q1 * W1f[5] + q2 * W1f[8] + b1[2]);
    if (h == 0) {
        uint4 u; u.x = pk2(r0, r1); u.y = pk2(r2, 0.f); u.z = 0u; u.w = 0u;
        *(uint4*)(table1 + (size_t)pt * T1S + 32) = u;   // cols 32..39 (35..39 zero)
    }
}

// ---------- K4: gather 16 neighbors x 2 points = 32 rows, K=40 GEMM, max over K
__global__ __launch_bounds__(256) void k4_main(const int* __restrict__ nidx,
        const float* __restrict__ b3, char* ws)
{
    const unsigned short* W3fT   = (const unsigned short*)(ws + WS_W3FT);
    const unsigned short* table1 = (const unsigned short*)(ws + WS_TABLE1);
    unsigned short* table2       = (unsigned short*)(ws + WS_TABLE2);
    int lane = threadIdx.x & 63;
    int wave = (blockIdx.x * 256 + threadIdx.x) >> 6;   // 0..8191
    int col = lane & 31, h = lane >> 5;
    F8 w0, w1, w2, zf;
    zf.u.x = zf.u.y = zf.u.z = zf.u.w = 0u;
    w0.u = *(const uint4*)(W3fT + col * 40 + 8 * h);
    w1.u = *(const uint4*)(W3fT + col * 40 + 16 + 8 * h);
    w2 = zf;
    if (h == 0) w2.u = *(const uint4*)(W3fT + col * 40 + 32);   // k=32..39 (35..39 zero)
    float b3v = b3[col];
    for (int gg = 0; gg < 8; gg++) {
        int base_pt = (wave * 8 + gg) * 2;
        int b = base_pt >> 16;
        int pt = base_pt + (col >> 4);                  // A row -> (point, k) pair
        int idx = nidx[pt * 16 + (col & 15)];
        const unsigned short* ap = table1 + (size_t)((b << 16) + idx) * T1S;
        F8 a0, a1, a2;
        a0.u = *(const uint4*)(ap + 8 * h);
        a1.u = *(const uint4*)(ap + 16 + 8 * h);
        a2 = zf;
        if (h == 0) a2.u = *(const uint4*)(ap + 32);
        float16 acc;
#pragma unroll
        for (int i = 0; i < 16; i++) acc[i] = 0.f;
        acc = __builtin_amdgcn_mfma_f32_32x32x16_bf16(a0.s, w0.s, acc, 0, 0, 0);
        acc = __builtin_amdgcn_mfma_f32_32x32x16_bf16(a1.s, w1.s, acc, 0, 0, 0);
        acc = __builtin_amdgcn_mfma_f32_32x32x16_bf16(a2.s, w2.s, acc, 0, 0, 0);
        float vA = acc[0], vB = acc[8];
#pragma unroll
        for (int r = 1; r < 8; r++) { vA = fmaxf(vA, acc[r]); vB = fmaxf(vB, acc[8 + r]); }
        vA = fmaxf(vA, __shfl_xor(vA, 32));
        vB = fmaxf(vB, __shfl_xor(vB, 32));
        vA = relu(vA + b3v);                            // b col-uniform: add after max
        vB = relu(vB + b3v);
        float val = h ? vB : vA;
        table2[(size_t)(base_pt + h) * T2S + 32 + col] = f2bf(val);
    }
}

// ---------- K5: out = cbr([feat, m] @ W4), transposed GEMM -> coalesced store --
__global__ __launch_bounds__(256) void k5_out(const float* __restrict__ b4,
        const char* __restrict__ ws, float* __restrict__ out)
{
    const unsigned short* W4fT   = (const unsigned short*)(ws + WS_W4FT);
    const unsigned short* table2 = (const unsigned short*)(ws + WS_TABLE2);
    int lane = threadIdx.x & 63;
    int wave = (blockIdx.x * 256 + threadIdx.x) >> 6;   // 0..2047
    int col = lane & 31, h = lane >> 5;
    F8 aw[4];
#pragma unroll
    for (int t = 0; t < 4; t++)
        aw[t].u = *(const uint4*)(W4fT + col * 64 + 16 * t + 8 * h);
    float b4v[16];
#pragma unroll
    for (int r = 0; r < 16; r++) b4v[r] = b4[(r & 3) + 8 * (r >> 2) + 4 * h];
    for (int tt = 0; tt < 2; tt++) {
        int base = (wave * 2 + tt) * 32;
        int b = base >> 16;
        int p = base + col;                             // B col = point
        int nl = p & (NPTS - 1);
        const unsigned short* bp = table2 + (size_t)p * T2S + 8 * h;
        F8 x0, x1, x2, x3;
        x0.u = *(const uint4*)(bp);
        x1.u = *(const uint4*)(bp + 16);
        x2.u = *(const uint4*)(bp + 32);
        x3.u = *(const uint4*)(bp + 48);
        float16 acc;
#pragma unroll
        for (int i = 0; i < 16; i++) acc[i] = 0.f;
        acc = __builtin_amdgcn_mfma_f32_32x32x16_bf16(aw[0].s, x0.s, acc, 0, 0, 0);
        acc = __builtin_amdgcn_mfma_f32_32x32x16_bf16(aw[1].s, x1.s, acc, 0, 0, 0);
        acc = __builtin_amdgcn_mfma_f32_32x32x16_bf16(aw[2].s, x2.s, acc, 0, 0, 0);
        acc = __builtin_amdgcn_mfma_f32_32x32x16_bf16(aw[3].s, x3.s, acc, 0, 0, 0);
        float* ob = out + (size_t)(b * 32) * NPTS + nl;
#pragma unroll
        for (int r = 0; r < 16; r++) {
            int o = (r & 3) + 8 * (r >> 2) + 4 * h;     // C row = out channel
            ob[(size_t)o * NPTS] = relu(acc[r] + b4v[r]);
        }
    }
}

extern "C" void kernel_launch(void* const* d_in, const int* in_sizes, int n_in,
                              void* d_out, int out_size, void* d_ws, size_t ws_size,
                              hipStream_t stream)
{
    const float* feature = (const float*)d_in[0];
    const float* xyz     = (const float*)d_in[1];
    const int*   nidx    = (const int*)d_in[2];
    const float* tW1 = (const float*)d_in[3];
    const float* ts1 = (const float*)d_in[4];
    const float* tb1 = (const float*)d_in[5];
    const float* tW2 = (const float*)d_in[6];
    const float* ts2 = (const float*)d_in[7];
    const float* tb2 = (const float*)d_in[8];
    const float* tW3 = (const float*)d_in[9];
    const float* ts3 = (const float*)d_in[10];
    const float* tb3 = (const float*)d_in[11];
    const float* tW4 = (const float*)d_in[12];
    const float* tb4 = (const float*)d_in[13];
    const float* W1  = (const float*)d_in[14];
    const float* s1  = (const float*)d_in[15];
    const float* b1  = (const float*)d_in[16];
    const float* W2  = (const float*)d_in[17];
    const float* s2  = (const float*)d_in[18];
    const float* b2  = (const float*)d_in[19];
    const float* W3  = (const float*)d_in[20];
    const float* s3  = (const float*)d_in[21];
    const float* b3  = (const float*)d_in[22];
    const float* W4  = (const float*)d_in[23];
    const float* s4  = (const float*)d_in[24];
    const float* b4  = (const float*)d_in[25];
    (void)in_sizes; (void)n_in; (void)out_size; (void)ws_size;

    char* ws = (char*)d_ws;
    float* hmax = (float*)(ws + WS_HMAX);

    k0_fold<<<1, 256, 0, stream>>>(tW1, ts1, tW2, ts2, W1, s1, W2, s2, W3, s3, W4, s4, ws);
    k1_tnet<<<512, 256, 0, stream>>>(xyz, tb1, tb2, ws, hmax);
    k3_prep<<<1024, 256, 0, stream>>>(feature, xyz, tW3, ts3, tb3, tW4, tb4, b1, b2, ws);
    k4_main<<<2048, 256, 0, stream>>>(nidx, b3, ws);
    k5_out<<<512, 256, 0, stream>>>(b4, ws, (float*)d_out);
}

// Round 4
// 172.394 us; speedup vs baseline: 4.6183x; 1.1862x over previous
//
#include <hip/hip_runtime.h>

#define NPTS  65536
#define BATCH 2
#define TOTAL (BATCH * NPTS)

typedef __attribute__((ext_vector_type(8)))  short short8;
typedef __attribute__((ext_vector_type(16))) float float16;
union F8 { uint4 u; short8 s; };

// ws byte offsets
#define WS_HMAX 0                              // fp32[128]
#define WS_T1A  1024                           // bf16[TOTAL][32]  f_nei, 64B rows
#define WS_T1B  (1024 + TOTAL * 64)            // bf16[TOTAL][4]   f_xyz(3)+0, 8B rows
#define WS_T2   (1024 + TOTAL * 64 + TOTAL * 8) // bf16[TOTAL][64] [feat(32), m(32)]

__device__ __forceinline__ unsigned short f2bf(float x) {
    unsigned u = __float_as_uint(x);
    return (unsigned short)((u + 0x7FFFu + ((u >> 16) & 1u)) >> 16);
}
__device__ __forceinline__ unsigned pk2(float a, float b) {
    return (unsigned)f2bf(a) | ((unsigned)f2bf(b) << 16);
}
__device__ __forceinline__ float relu(float x) { return x > 0.f ? x : 0.f; }
__device__ __forceinline__ uint4 pk8(const float* e) {
    uint4 u;
    u.x = pk2(e[0], e[1]); u.y = pk2(e[2], e[3]);
    u.z = pk2(e[4], e[5]); u.w = pk2(e[6], e[7]);
    return u;
}

// ---------- K1: tnet trunk (3->16->64) MFMA + block-level max reduce + few atomics
__global__ __launch_bounds__(256) void k1_tnet(const float* __restrict__ xyz,
        const float* __restrict__ tW1, const float* __restrict__ ts1, const float* __restrict__ tb1,
        const float* __restrict__ tW2, const float* __restrict__ ts2, const float* __restrict__ tb2,
        float* __restrict__ hmax)
{
    __shared__ float red[4][64];
    int lane = threadIdx.x & 63, wv = threadIdx.x >> 6;
    int col = lane & 31, h = lane >> 5;
    int blk_base = blockIdx.x * 512;           // 256 blocks x 512 pts
    int b = blk_base >> 16;                    // block never crosses batch

    // inline fold: A-weights (tW1*ts1) and B-fragments (tW2^T * ts2) per lane
    float aw0[8], aw1[8], aw2[8], bb[8];
#pragma unroll
    for (int j = 0; j < 8; j++) {
        int k = 8 * h + j; float s = ts1[k];
        aw0[j] = tW1[k] * s; aw1[j] = tW1[16 + k] * s; aw2[j] = tW1[32 + k] * s;
        bb[j] = tb1[k];
    }
    float e[8];
    F8 bf0, bf1;
#pragma unroll
    for (int j = 0; j < 8; j++) e[j] = tW2[(8 * h + j) * 64 + col] * ts2[col];
    bf0.u = pk8(e);
#pragma unroll
    for (int j = 0; j < 8; j++) e[j] = tW2[(8 * h + j) * 64 + 32 + col] * ts2[32 + col];
    bf1.u = pk8(e);

    float16 m0, m1;
#pragma unroll
    for (int i = 0; i < 16; i++) { m0[i] = -1e30f; m1[i] = -1e30f; }

    for (int g = 0; g < 4; g++) {
        int base = blk_base + wv * 128 + g * 32;
        const float* xp = xyz + (size_t)(base + col) * 3;
        float x0 = xp[0], x1 = xp[1], x2 = xp[2];
        float hv[8];
#pragma unroll
        for (int j = 0; j < 8; j++)
            hv[j] = relu(x0 * aw0[j] + x1 * aw1[j] + x2 * aw2[j] + bb[j]);
        F8 af; af.u = pk8(hv);
        float16 z;
#pragma unroll
        for (int i = 0; i < 16; i++) z[i] = 0.f;
        float16 c0 = __builtin_amdgcn_mfma_f32_32x32x16_bf16(af.s, bf0.s, z, 0, 0, 0);
        float16 c1 = __builtin_amdgcn_mfma_f32_32x32x16_bf16(af.s, bf1.s, z, 0, 0, 0);
#pragma unroll
        for (int i = 0; i < 16; i++) { m0[i] = fmaxf(m0[i], c0[i]); m1[i] = fmaxf(m1[i], c1[i]); }
    }
    float v0 = m0[0], v1 = m1[0];
#pragma unroll
    for (int i = 1; i < 16; i++) { v0 = fmaxf(v0, m0[i]); v1 = fmaxf(v1, m1[i]); }
    v0 = fmaxf(v0, __shfl_xor(v0, 32));
    v1 = fmaxf(v1, __shfl_xor(v1, 32));
    if (h == 0) { red[wv][col] = v0; red[wv][32 + col] = v1; }
    __syncthreads();
    if (threadIdx.x < 64) {
        int c = threadIdx.x;
        float m = fmaxf(fmaxf(red[0][c], red[1][c]), fmaxf(red[2][c], red[3][c]));
        float val = relu(m + tb2[c]);          // bias/relu after max: monotone, valid
        atomicMax((unsigned*)(hmax + b * 64 + c), __float_as_uint(val));
    }
}

// ---------- K3: per-block tnet head + f_nei GEMM + raw feat bf16 + f_xyz ----
__global__ __launch_bounds__(256) void k3_prep(const float* __restrict__ feature,
        const float* __restrict__ xyz,
        const float* __restrict__ tW3, const float* __restrict__ ts3, const float* __restrict__ tb3,
        const float* __restrict__ tW4, const float* __restrict__ tb4,
        const float* __restrict__ W1,  const float* __restrict__ s1, const float* __restrict__ b1,
        const float* __restrict__ W2,  const float* __restrict__ s2, const float* __restrict__ b2,
        char* ws)
{
    __shared__ float Tsh[9];
    const float* hmax = (const float*)(ws + WS_HMAX);
    unsigned short* t1a = (unsigned short*)(ws + WS_T1A);
    unsigned short* t1b = (unsigned short*)(ws + WS_T1B);
    unsigned short* t2  = (unsigned short*)(ws + WS_T2);
    int lane = threadIdx.x & 63, wv = threadIdx.x >> 6;
    int col = lane & 31, h = lane >> 5;
    int base = (blockIdx.x * 4 + wv) * 32;     // 1024 blocks x 128 pts
    int b = base >> 16;                        // block-uniform (128 | 65536)
    int pt = base + col;

    // wave 0: tnet head once per block -> Tsh
    if (wv == 0) {
        int lc = lane & 15;
        float ha = 0.f;
        for (int i = 0; i < 64; i++) ha += hmax[b * 64 + i] * tW3[i * 16 + lc];
        float h3 = relu(ha * ts3[lc] + tb3[lc]);
        float T[9];
#pragma unroll
        for (int j = 0; j < 9; j++) T[j] = tb4[j];
        for (int c = 0; c < 16; c++) {
            float hc = __shfl(h3, c, 64);
#pragma unroll
            for (int j = 0; j < 9; j++) T[j] += hc * tW4[c * 9 + j];
        }
        T[0] += 1.f; T[4] += 1.f; T[8] += 1.f;
        if (lane < 9) Tsh[lane] = T[lane];
    }

    // A-fragments: folded W2^T ([co=col][ci]) inline
    float e[8];
    float sc = s2[col];
    F8 a0, a1;
#pragma unroll
    for (int j = 0; j < 8; j++) e[j] = W2[(8 * h + j) * 32 + col] * sc;
    a0.u = pk8(e);
#pragma unroll
    for (int j = 0; j < 8; j++) e[j] = W2[(16 + 8 * h + j) * 32 + col] * sc;
    a1.u = pk8(e);

    // B-fragments: feat channels for point pt (+ raw bf16 copy to t2)
    const float* fb = feature + (size_t)b * 32 * NPTS + (pt & (NPTS - 1));
    float v[8];
    F8 b0, b1f;
#pragma unroll
    for (int j = 0; j < 8; j++) v[j] = fb[(size_t)(8 * h + j) * NPTS];
    b0.u = pk8(v);
#pragma unroll
    for (int j = 0; j < 8; j++) v[j] = fb[(size_t)(16 + 8 * h + j) * NPTS];
    b1f.u = pk8(v);
    *(uint4*)(t2 + (size_t)pt * 64 + 8 * h) = b0.u;
    *(uint4*)(t2 + (size_t)pt * 64 + 16 + 8 * h) = b1f.u;

    float16 acc;
#pragma unroll
    for (int i = 0; i < 16; i++) acc[i] = 0.f;
    acc = __builtin_amdgcn_mfma_f32_32x32x16_bf16(a0.s, b0.s, acc, 0, 0, 0);
    acc = __builtin_amdgcn_mfma_f32_32x32x16_bf16(a1.s, b1f.s, acc, 0, 0, 0);

    float b2v[16];
#pragma unroll
    for (int r = 0; r < 16; r++) b2v[r] = b2[(r & 3) + 8 * (r >> 2) + 4 * h];
#pragma unroll
    for (int q = 0; q < 4; q++) {
        int r = 4 * q;
        uint2 u;
        u.x = pk2(relu(acc[r] + b2v[r]), relu(acc[r + 1] + b2v[r + 1]));
        u.y = pk2(relu(acc[r + 2] + b2v[r + 2]), relu(acc[r + 3] + b2v[r + 3]));
        *(uint2*)(t1a + (size_t)pt * 32 + 8 * q + 4 * h) = u;
    }

    __syncthreads();
    float T[9];
#pragma unroll
    for (int j = 0; j < 9; j++) T[j] = Tsh[j];
    const float* xp = xyz + (size_t)pt * 3;
    float x0 = xp[0], x1 = xp[1], x2 = xp[2];
    float q0 = x0 * T[0] + x1 * T[3] + x2 * T[6];
    float q1 = x0 * T[1] + x1 * T[4] + x2 * T[7];
    float q2 = x0 * T[2] + x1 * T[5] + x2 * T[8];
    float r0 = relu((q0 * W1[0] + q1 * W1[3] + q2 * W1[6]) * s1[0] + b1[0]);
    float r1 = relu((q0 * W1[1] + q1 * W1[4] + q2 * W1[7]) * s1[1] + b1[1]);
    float r2 = relu((q0 * W1[2] + q1 * W1[5] + q2 * W1[8]) * s1[2] + b1[2]);
    if (h == 0) {
        uint2 u; u.x = pk2(r0, r1); u.y = pk2(r2, 0.f);
        *(uint2*)(t1b + (size_t)pt * 4) = u;
    }
}

// ---------- K4: gather 16 nbrs x 2 pts = 32 rows, K=40 GEMM, max over K ------
__global__ __launch_bounds__(256) void k4_main(const int* __restrict__ nidx,
        const float* __restrict__ W3, const float* __restrict__ s3, const float* __restrict__ b3,
        char* ws)
{
    const unsigned short* t1a = (const unsigned short*)(ws + WS_T1A);
    const unsigned short* t1b = (const unsigned short*)(ws + WS_T1B);
    unsigned short* t2        = (unsigned short*)(ws + WS_T2);
    int lane = threadIdx.x & 63;
    int wave = (blockIdx.x * 256 + threadIdx.x) >> 6;   // 0..8191
    int col = lane & 31, h = lane >> 5;

    // B-fragments: folded W3^T inline (k>=35 zero)
    float e[8];
    float sc = s3[col];
    F8 w0, w1, w2, zf;
    zf.u.x = zf.u.y = zf.u.z = zf.u.w = 0u;
#pragma unroll
    for (int j = 0; j < 8; j++) e[j] = W3[(8 * h + j) * 32 + col] * sc;
    w0.u = pk8(e);
#pragma unroll
    for (int j = 0; j < 8; j++) e[j] = W3[(16 + 8 * h + j) * 32 + col] * sc;
    w1.u = pk8(e);
    w2 = zf;
    if (h == 0) {
        float e2[8] = {0.f, 0.f, 0.f, 0.f, 0.f, 0.f, 0.f, 0.f};
#pragma unroll
        for (int j = 0; j < 3; j++) e2[j] = W3[(32 + j) * 32 + col] * sc;
        w2.u = pk8(e2);
    }
    float b3v = b3[col];

    int idxs[8];
#pragma unroll
    for (int gg = 0; gg < 8; gg++) {
        int pt = (wave * 8 + gg) * 2 + (col >> 4);
        idxs[gg] = nidx[pt * 16 + (col & 15)];
    }

    for (int gg = 0; gg < 8; gg++) {
        int base_pt = (wave * 8 + gg) * 2;
        int b = base_pt >> 16;
        size_t row = (size_t)((b << 16) + idxs[gg]);
        F8 a0, a1, a2;
        a0.u = *(const uint4*)(t1a + row * 32 + 8 * h);
        a1.u = *(const uint4*)(t1a + row * 32 + 16 + 8 * h);
        a2 = zf;
        if (h == 0) {
            uint2 q = *(const uint2*)(t1b + row * 4);
            a2.u.x = q.x; a2.u.y = q.y;
        }
        float16 acc;
#pragma unroll
        for (int i = 0; i < 16; i++) acc[i] = 0.f;
        acc = __builtin_amdgcn_mfma_f32_32x32x16_bf16(a0.s, w0.s, acc, 0, 0, 0);
        acc = __builtin_amdgcn_mfma_f32_32x32x16_bf16(a1.s, w1.s, acc, 0, 0, 0);
        acc = __builtin_amdgcn_mfma_f32_32x32x16_bf16(a2.s, w2.s, acc, 0, 0, 0);
        float vA = acc[0], vB = acc[8];
#pragma unroll
        for (int r = 1; r < 8; r++) { vA = fmaxf(vA, acc[r]); vB = fmaxf(vB, acc[8 + r]); }
        vA = fmaxf(vA, __shfl_xor(vA, 32));
        vB = fmaxf(vB, __shfl_xor(vB, 32));
        vA = relu(vA + b3v);
        vB = relu(vB + b3v);
        float val = h ? vB : vA;
        t2[(size_t)(base_pt + h) * 64 + 32 + col] = f2bf(val);
    }
}

// ---------- K5: out = cbr([feat, m] @ W4), transposed GEMM -> coalesced store -
__global__ __launch_bounds__(256) void k5_out(
        const float* __restrict__ W4, const float* __restrict__ s4, const float* __restrict__ b4,
        const char* __restrict__ ws, float* __restrict__ out)
{
    const unsigned short* t2 = (const unsigned short*)(ws + WS_T2);
    int lane = threadIdx.x & 63;
    int wave = (blockIdx.x * 256 + threadIdx.x) >> 6;   // 0..2047
    int col = lane & 31, h = lane >> 5;

    float e[8];
    float sc = s4[col];
    F8 aw[4];
#pragma unroll
    for (int t = 0; t < 4; t++) {
#pragma unroll
        for (int j = 0; j < 8; j++) e[j] = W4[(16 * t + 8 * h + j) * 32 + col] * sc;
        aw[t].u = pk8(e);
    }
    float b4v[16];
#pragma unroll
    for (int r = 0; r < 16; r++) b4v[r] = b4[(r & 3) + 8 * (r >> 2) + 4 * h];

    for (int tt = 0; tt < 2; tt++) {
        int base = (wave * 2 + tt) * 32;
        int b = base >> 16;
        int p = base + col;
        int nl = p & (NPTS - 1);
        const unsigned short* bp = t2 + (size_t)p * 64 + 8 * h;
        F8 x0, x1, x2, x3;
        x0.u = *(const uint4*)(bp);
        x1.u = *(const uint4*)(bp + 16);
        x2.u = *(const uint4*)(bp + 32);
        x3.u = *(const uint4*)(bp + 48);
        float16 acc;
#pragma unroll
        for (int i = 0; i < 16; i++) acc[i] = 0.f;
        acc = __builtin_amdgcn_mfma_f32_32x32x16_bf16(aw[0].s, x0.s, acc, 0, 0, 0);
        acc = __builtin_amdgcn_mfma_f32_32x32x16_bf16(aw[1].s, x1.s, acc, 0, 0, 0);
        acc = __builtin_amdgcn_mfma_f32_32x32x16_bf16(aw[2].s, x2.s, acc, 0, 0, 0);
        acc = __builtin_amdgcn_mfma_f32_32x32x16_bf16(aw[3].s, x3.s, acc, 0, 0, 0);
        float* ob = out + (size_t)(b * 32) * NPTS + nl;
#pragma unroll
        for (int r = 0; r < 16; r++) {
            int o = (r & 3) + 8 * (r >> 2) + 4 * h;
            ob[(size_t)o * NPTS] = relu(acc[r] + b4v[r]);
        }
    }
}

extern "C" void kernel_launch(void* const* d_in, const int* in_sizes, int n_in,
                              void* d_out, int out_size, void* d_ws, size_t ws_size,
                              hipStream_t stream)
{
    const float* feature = (const float*)d_in[0];
    const float* xyz     = (const float*)d_in[1];
    const int*   nidx    = (const int*)d_in[2];
    const float* tW1 = (const float*)d_in[3];
    const float* ts1 = (const float*)d_in[4];
    const float* tb1 = (const float*)d_in[5];
    const float* tW2 = (const float*)d_in[6];
    const float* ts2 = (const float*)d_in[7];
    const float* tb2 = (const float*)d_in[8];
    const float* tW3 = (const float*)d_in[9];
    const float* ts3 = (const float*)d_in[10];
    const float* tb3 = (const float*)d_in[11];
    const float* tW4 = (const float*)d_in[12];
    const float* tb4 = (const float*)d_in[13];
    const float* W1  = (const float*)d_in[14];
    const float* s1  = (const float*)d_in[15];
    const float* b1  = (const float*)d_in[16];
    const float* W2  = (const float*)d_in[17];
    const float* s2  = (const float*)d_in[18];
    const float* b2  = (const float*)d_in[19];
    const float* W3  = (const float*)d_in[20];
    const float* s3  = (const float*)d_in[21];
    const float* b3  = (const float*)d_in[22];
    const float* W4  = (const float*)d_in[23];
    const float* s4  = (const float*)d_in[24];
    const float* b4  = (const float*)d_in[25];
    (void)in_sizes; (void)n_in; (void)out_size; (void)ws_size;

    char* ws = (char*)d_ws;
    float* hmax = (float*)(ws + WS_HMAX);

    hipMemsetAsync(hmax, 0, 512, stream);
    k1_tnet<<<256, 256, 0, stream>>>(xyz, tW1, ts1, tb1, tW2, ts2, tb2, hmax);
    k3_prep<<<1024, 256, 0, stream>>>(feature, xyz, tW3, ts3, tb3, tW4, tb4,
                                      W1, s1, b1, W2, s2, b2, ws);
    k4_main<<<2048, 256, 0, stream>>>(nidx, W3, s3, b3, ws);
    k5_out<<<512, 256, 0, stream>>>(W4, s4, b4, ws, (float*)d_out);
}